// Round 6
// baseline (761.499 us; speedup 1.0000x reference)
//
#include <hip/hip_runtime.h>

#define NNODES 100000
#define NEDGES 1600000
#define HID    128
#define INDIM  64

typedef __attribute__((ext_vector_type(8))) short bf16x8;
typedef __attribute__((ext_vector_type(4))) float f32x4;
typedef __attribute__((ext_vector_type(2))) _Float16 half2_t;

__device__ __forceinline__ unsigned pack_bf16x2(float a, float b) {
  unsigned ua = __float_as_uint(a), ub = __float_as_uint(b);
  ua = (ua + 0x7fffu + ((ua >> 16) & 1u)) >> 16;
  ub = (ub + 0x7fffu + ((ub >> 16) & 1u)) >> 16;
  return ua | (ub << 16);
}
__device__ __forceinline__ unsigned short bf16r(float x) {
  unsigned u = __float_as_uint(x);
  u = (u + 0x7fffu + ((u >> 16) & 1u)) >> 16;
  return (unsigned short)u;
}
__device__ __forceinline__ float bf16lo(unsigned u) { return __uint_as_float(u << 16); }
__device__ __forceinline__ float bf16hi(unsigned u) { return __uint_as_float(u & 0xffff0000u); }
__device__ __forceinline__ unsigned f16x2(float a, float b) {
  half2_t h; h.x = (_Float16)a; h.y = (_Float16)b;
  return __builtin_bit_cast(unsigned, h);
}

// ============================ x -> fp16 ============================

__global__ __launch_bounds__(256) void xprep_kernel(const float* __restrict__ x, uint2* __restrict__ xh) {
  int i = blockIdx.x * 256 + threadIdx.x;
  if (i >= NNODES * INDIM / 4) return;
  float4 v = reinterpret_cast<const float4*>(x)[i];
  xh[i] = make_uint2(f16x2(v.x, v.y), f16x2(v.z, v.w));
}

// ============================ graph preprocessing ============================
// u64 packed histogram: count [63:40], wdeg Q8.24 [39:0]; atomic return = per-edge rank.

__global__ __launch_bounds__(256) void hist_kernel(const int* __restrict__ ei, const float* __restrict__ ew,
                                                   unsigned long long* __restrict__ packed,
                                                   unsigned* __restrict__ rank) {
  int e = blockIdx.x * 256 + threadIdx.x;
  if (e >= NEDGES) return;
  int d = ei[NEDGES + e];
  unsigned long long inc = (1ULL << 40) | (unsigned long long)(ew[e] * 16777216.0f + 0.5f);
  unsigned long long old = atomicAdd(&packed[d], inc);
  rank[e] = (unsigned)(old >> 40);
}

// counts padded to multiple of 4 (branchless agg loop); dinv from Q8.24 wdeg.
__global__ __launch_bounds__(256) void degcnt_kernel(const unsigned long long* __restrict__ packed,
                                                     unsigned* __restrict__ counts, float* __restrict__ dinv) {
  int i = blockIdx.x * 256 + threadIdx.x;
  if (i >= NNODES) return;
  unsigned long long r = packed[i];
  counts[i] = ((unsigned)(r >> 40) + 3u) & ~3u;
  float wd = (float)(r & 0xFFFFFFFFFFULL) * (1.0f / 16777216.0f);
  dinv[i] = rsqrtf(wd + 1.0f);
}

__global__ __launch_bounds__(256) void scan1_kernel(const unsigned* __restrict__ counts,
                                                    unsigned* __restrict__ part, unsigned* __restrict__ bsums) {
  __shared__ unsigned s[256];
  int i = blockIdx.x * 256 + threadIdx.x;
  unsigned v = (i < NNODES) ? counts[i] : 0u;
  s[threadIdx.x] = v;
  __syncthreads();
  for (int off = 1; off < 256; off <<= 1) {
    unsigned t = (threadIdx.x >= off) ? s[threadIdx.x - off] : 0u;
    __syncthreads();
    s[threadIdx.x] += t;
    __syncthreads();
  }
  if (i < NNODES) part[i] = s[threadIdx.x] - v;
  if (threadIdx.x == 255) bsums[blockIdx.x] = s[255];
}

__global__ void scan2_kernel(unsigned* __restrict__ bsums, unsigned* __restrict__ row_ofs, int nb) {
  __shared__ unsigned s[512];
  unsigned v = ((int)threadIdx.x < nb) ? bsums[threadIdx.x] : 0u;
  s[threadIdx.x] = v;
  __syncthreads();
  for (int off = 1; off < 512; off <<= 1) {
    unsigned t = (threadIdx.x >= off) ? s[threadIdx.x - off] : 0u;
    __syncthreads();
    s[threadIdx.x] += t;
    __syncthreads();
  }
  if ((int)threadIdx.x < nb) bsums[threadIdx.x] = s[threadIdx.x] - v;
  if (threadIdx.x == 511) row_ofs[NNODES] = s[511];
}

__global__ __launch_bounds__(256) void scan3_kernel(unsigned* __restrict__ row_ofs,
                                                    const unsigned* __restrict__ bsums) {
  int i = blockIdx.x * 256 + threadIdx.x;
  if (i < NNODES) row_ofs[i] += bsums[blockIdx.x];
}

// edges[pos] = {src, float_bits(norm)}; pos = padded row_ofs[d] + rank[e]. Pad slots stay 0 (pre-zeroed).
__global__ __launch_bounds__(256) void scatter_kernel(const int* __restrict__ ei, const float* __restrict__ ew,
                                                      const float* __restrict__ dinv,
                                                      const unsigned* __restrict__ rank,
                                                      const unsigned* __restrict__ row_ofs,
                                                      uint2* __restrict__ edges) {
  int e = blockIdx.x * 256 + threadIdx.x;
  if (e >= NEDGES) return;
  int s = ei[e];
  int d = ei[NEDGES + e];
  unsigned pos = row_ofs[d] + rank[e];
  uint2 rec;
  rec.x = (unsigned)s;
  rec.y = __float_as_uint(ew[e] * dinv[s] * dinv[d]);
  edges[pos] = rec;
}

// ============================ W prep: all 5 layers, transpose + bf16 ============================
// wt layout: [0, 9216) layer0 (128 x 72); then 4 x (128 x 136).

__global__ __launch_bounds__(256) void wtprep_kernel(const float* __restrict__ W_in,
                                                     const float* __restrict__ W_mid,
                                                     const float* __restrict__ W_out,
                                                     unsigned short* __restrict__ wt) {
  int idx = blockIdx.x * 256 + threadIdx.x;
  const int S0 = HID * 72;
  const int SL = HID * 136;
  if (idx >= S0 + 4 * SL) return;
  float v = 0.f;
  if (idx < S0) {
    int c = idx / 72, k = idx % 72;
    if (k < INDIM) v = W_in[(size_t)k * HID + c];
  } else {
    int r = idx - S0;
    int l = r / SL, j = r % SL;
    int c = j / 136, k = j % 136;
    const float* W = (l < 3) ? (W_mid + (size_t)l * HID * HID) : W_out;
    if (k < HID) v = W[(size_t)k * HID + c];
  }
  wt[idx] = bf16r(v);
}

// ============================ aggregation: t = S · fh (fp16 rows, fp32 accum) ============================
// LANES=64: one wave per node -> scalar edge stream; LANES=32 (layer 0): 2 nodes/wave.
// Branchless: edge lists padded to x4 with zero records.

template <int LANES>
__global__ __launch_bounds__(256) void agg_kernel(const unsigned* __restrict__ hh,
                                                  const unsigned* __restrict__ row_ofs,
                                                  const uint2* __restrict__ edges,
                                                  const float* __restrict__ dinv,
                                                  unsigned* __restrict__ tb) {
  int gid = blockIdx.x * 256 + threadIdx.x;
  int node = gid / LANES;
  const int lane = gid % LANES;
  if (LANES == 64) node = __builtin_amdgcn_readfirstlane(node);
  const unsigned ro = row_ofs[node], re = row_ofs[node + 1];
  const float di = dinv[node];
  const float wself = di * di;
  half2_t sv = __builtin_bit_cast(half2_t, hh[(unsigned)node * LANES + lane]);
  float acc0 = (float)sv.x * wself;
  float acc1 = (float)sv.y * wself;
  for (unsigned e = ro; e < re; e += 4) {
    uint2 p0 = edges[e];
    uint2 p1 = edges[e + 1];
    uint2 p2 = edges[e + 2];
    uint2 p3 = edges[e + 3];
    half2_t v0 = __builtin_bit_cast(half2_t, hh[p0.x * LANES + lane]);
    half2_t v1 = __builtin_bit_cast(half2_t, hh[p1.x * LANES + lane]);
    half2_t v2 = __builtin_bit_cast(half2_t, hh[p2.x * LANES + lane]);
    half2_t v3 = __builtin_bit_cast(half2_t, hh[p3.x * LANES + lane]);
    const float w0 = __uint_as_float(p0.y), w1 = __uint_as_float(p1.y);
    const float w2 = __uint_as_float(p2.y), w3 = __uint_as_float(p3.y);
    acc0 = fmaf((float)v0.x, w0, acc0); acc1 = fmaf((float)v0.y, w0, acc1);
    acc0 = fmaf((float)v1.x, w1, acc0); acc1 = fmaf((float)v1.y, w1, acc1);
    acc0 = fmaf((float)v2.x, w2, acc0); acc1 = fmaf((float)v2.y, w2, acc1);
    acc0 = fmaf((float)v3.x, w3, acc0); acc1 = fmaf((float)v3.y, w3, acc1);
  }
  tb[(unsigned)node * LANES + lane] = pack_bf16x2(acc0, acc1);
}

// ============================ GEMM (bf16 MFMA) + fused BN stats ============================
// h = t @ W + b (bf16 out); per-block column sums/sumsq of the rounded h -> global atomics.

template <int K>
__global__ __launch_bounds__(256) void gemm_kernel(const unsigned short* __restrict__ A,
                                                   const unsigned short* __restrict__ Wt,
                                                   const float* __restrict__ bias,
                                                   unsigned short* __restrict__ out,
                                                   float* __restrict__ stats) {
  constexpr int KP = (K == 128) ? 136 : 72;
  __shared__ __align__(16) unsigned short sW[HID * KP];
  __shared__ __align__(16) unsigned short sA[64 * KP];
  __shared__ float sS[128], sQ[128];
  const int tid = threadIdx.x;
  if (tid < 128) { sS[tid] = 0.f; sQ[tid] = 0.f; }

  {
    const uint4* g = (const uint4*)Wt;
    uint4* s = (uint4*)sW;
    const int n = HID * KP / 8;
    for (int i = tid; i < n; i += 256) s[i] = g[i];
  }

  const int row0 = blockIdx.x * 64;
  constexpr int CPR = K / 8;
  const uint4* Ag = (const uint4*)A;
#pragma unroll
  for (int i = tid; i < 64 * CPR; i += 256) {
    int row = i / CPR, ch = i % CPR;
    int grow = row0 + row;
    uint4 v = make_uint4(0u, 0u, 0u, 0u);
    if (grow < NNODES) v = Ag[(size_t)grow * CPR + ch];
    *reinterpret_cast<uint4*>(&sA[row * KP + ch * 8]) = v;
  }
  __syncthreads();

  const int wid = tid >> 6;
  const int lane = tid & 63;
  const int wrow = wid * 16;
  const int fr = lane & 15;
  const int fk = (lane >> 4) * 8;

  f32x4 acc[8];
#pragma unroll
  for (int cf = 0; cf < 8; cf++) acc[cf] = (f32x4){0.f, 0.f, 0.f, 0.f};

  bf16x8 afrag[K / 32];
#pragma unroll
  for (int ks = 0; ks < K / 32; ks++)
    afrag[ks] = *reinterpret_cast<const bf16x8*>(&sA[(wrow + fr) * KP + ks * 32 + fk]);

#pragma unroll
  for (int cf = 0; cf < 8; cf++) {
#pragma unroll
    for (int ks = 0; ks < K / 32; ks++) {
      bf16x8 b = *reinterpret_cast<const bf16x8*>(&sW[(cf * 16 + fr) * KP + ks * 32 + fk]);
      acc[cf] = __builtin_amdgcn_mfma_f32_16x16x32_bf16(afrag[ks], b, acc[cf], 0, 0, 0);
    }
  }

  const int orow = (lane >> 4) * 4;
#pragma unroll
  for (int cf = 0; cf < 8; cf++) {
    const int col = cf * 16 + fr;
    const float bv = bias[col];
    float s = 0.f, q = 0.f;
#pragma unroll
    for (int j = 0; j < 4; j++) {
      int grow = row0 + wrow + orow + j;
      float val = 0.f;
      if (grow < NNODES) {
        unsigned short o = bf16r(acc[cf][j] + bv);
        out[(size_t)grow * HID + col] = o;
        val = __uint_as_float((unsigned)o << 16);
      }
      s += val; q += val * val;
    }
    s += __shfl_xor(s, 16); s += __shfl_xor(s, 32);
    q += __shfl_xor(q, 16); q += __shfl_xor(q, 32);
    if (lane < 16) { atomicAdd(&sS[col], s); atomicAdd(&sQ[col], q); }
  }
  __syncthreads();
  if (tid < 128) {
    atomicAdd(&stats[tid],       sS[tid]);
    atomicAdd(&stats[128 + tid], sQ[tid]);
  }
}

// ============================ BN apply (inline finalize): fh = relu(bn(h)) fp16 ============================

__global__ __launch_bounds__(256) void bnapply_kernel(const uint4* __restrict__ hb,
                                                      const float* __restrict__ stats,
                                                      const float* __restrict__ gamma,
                                                      const float* __restrict__ beta,
                                                      uint4* __restrict__ fh) {
  __shared__ float sc[128], sh[128];
  if (threadIdx.x < 128) {
    int c = threadIdx.x;
    float mu  = stats[c] * (1.0f / NNODES);
    float var = fmaf(-mu, mu, stats[128 + c] * (1.0f / NNODES));
    float scale = gamma[c] * rsqrtf(var + 1e-5f);
    sc[c] = scale;
    sh[c] = fmaf(-mu, scale, beta[c]);
  }
  __syncthreads();
  int i = blockIdx.x * 256 + threadIdx.x;   // grid exact: N*16/256
  uint4 v = hb[i];
  int cb = (i & 15) * 8;
  float r0 = fmaxf(fmaf(bf16lo(v.x), sc[cb + 0], sh[cb + 0]), 0.f);
  float r1 = fmaxf(fmaf(bf16hi(v.x), sc[cb + 1], sh[cb + 1]), 0.f);
  float r2 = fmaxf(fmaf(bf16lo(v.y), sc[cb + 2], sh[cb + 2]), 0.f);
  float r3 = fmaxf(fmaf(bf16hi(v.y), sc[cb + 3], sh[cb + 3]), 0.f);
  float r4 = fmaxf(fmaf(bf16lo(v.z), sc[cb + 4], sh[cb + 4]), 0.f);
  float r5 = fmaxf(fmaf(bf16hi(v.z), sc[cb + 5], sh[cb + 5]), 0.f);
  float r6 = fmaxf(fmaf(bf16lo(v.w), sc[cb + 6], sh[cb + 6]), 0.f);
  float r7 = fmaxf(fmaf(bf16hi(v.w), sc[cb + 7], sh[cb + 7]), 0.f);
  fh[i] = make_uint4(f16x2(r0, r1), f16x2(r2, r3), f16x2(r4, r5), f16x2(r6, r7));
}

// ============================ final BN (no ReLU) -> fp32 out ============================

__global__ __launch_bounds__(256) void normout_kernel(const unsigned* __restrict__ hb,
                                                      const float* __restrict__ stats,
                                                      const float* __restrict__ gamma,
                                                      const float* __restrict__ beta,
                                                      float2* __restrict__ out) {
  __shared__ float sc[128], sh[128];
  if (threadIdx.x < 128) {
    int c = threadIdx.x;
    float mu  = stats[c] * (1.0f / NNODES);
    float var = fmaf(-mu, mu, stats[128 + c] * (1.0f / NNODES));
    float scale = gamma[c] * rsqrtf(var + 1e-5f);
    sc[c] = scale;
    sh[c] = fmaf(-mu, scale, beta[c]);
  }
  __syncthreads();
  int i = blockIdx.x * 256 + threadIdx.x;   // grid exact: N*64/256
  unsigned u = hb[i];
  int c = (i & 63) * 2;
  out[i] = make_float2(fmaf(bf16lo(u), sc[c],     sh[c]),
                       fmaf(bf16hi(u), sc[c + 1], sh[c + 1]));
}

// ============================ launch ============================

extern "C" void kernel_launch(void* const* d_in, const int* in_sizes, int n_in,
                              void* d_out, int out_size, void* d_ws, size_t ws_size,
                              hipStream_t stream) {
  const float* x     = (const float*)d_in[0];
  const int*   ei    = (const int*)d_in[1];
  const float* ew    = (const float*)d_in[2];
  const float* W_in  = (const float*)d_in[3];
  const float* b_in  = (const float*)d_in[4];
  const float* W_mid = (const float*)d_in[5];
  const float* b_mid = (const float*)d_in[6];
  const float* W_out = (const float*)d_in[7];
  const float* b_out = (const float*)d_in[8];
  const float* gamma = (const float*)d_in[9];
  const float* beta  = (const float*)d_in[10];

  char* p = (char*)d_ws;
  auto alloc = [&](size_t bytes) -> char* {
    char* r = p;
    p += (bytes + 255) & ~(size_t)255;
    return r;
  };
  const size_t EPAD = (size_t)NEDGES + 3 * (size_t)NNODES + 8;   // padded edge capacity
  unsigned long long* packed = (unsigned long long*)alloc((size_t)NNODES * 8);
  float*    stats   = (float*)alloc(5 * 256 * 4);
  uint2*    edges   = (uint2*)alloc(EPAD * 8);
  size_t zbytes = (size_t)(p - (char*)d_ws);          // packed + stats + edges zeroed
  unsigned* counts  = (unsigned*)alloc((size_t)NNODES * 4);
  float*    dinv    = (float*)alloc((size_t)NNODES * 4);
  unsigned* row_ofs = (unsigned*)alloc((size_t)(NNODES + 1) * 4);
  unsigned* bsums   = (unsigned*)alloc(512 * 4);
  unsigned* rank    = (unsigned*)alloc((size_t)NEDGES * 4);
  unsigned* xh      = (unsigned*)alloc((size_t)NNODES * INDIM * 2);
  unsigned short* h = (unsigned short*)alloc((size_t)NNODES * HID * 2);
  unsigned short* t = (unsigned short*)alloc((size_t)NNODES * HID * 2);
  unsigned short* wt = (unsigned short*)alloc((size_t)(HID * 72 + 4 * HID * 136) * 2);
  uint4*    fh      = (uint4*)d_out;                  // fp16 f(h) scratch lives in d_out (25.6 of 51.2 MB)

  hipMemsetAsync(d_ws, 0, zbytes, stream);

  const int eb = (NEDGES + 255) / 256;
  const int nb = (NNODES + 255) / 256;
  const int gb = (NNODES + 63) / 64;

  xprep_kernel<<<(NNODES * INDIM / 4 + 255) / 256, 256, 0, stream>>>(x, (uint2*)xh);
  hist_kernel<<<eb, 256, 0, stream>>>(ei, ew, packed, rank);
  degcnt_kernel<<<nb, 256, 0, stream>>>(packed, counts, dinv);
  scan1_kernel<<<nb, 256, 0, stream>>>(counts, row_ofs, bsums);
  scan2_kernel<<<1, 512, 0, stream>>>(bsums, row_ofs, nb);
  scan3_kernel<<<nb, 256, 0, stream>>>(row_ofs, bsums);
  scatter_kernel<<<eb, 256, 0, stream>>>(ei, ew, dinv, rank, row_ofs, edges);
  wtprep_kernel<<<(HID * 72 + 4 * HID * 136 + 255) / 256, 256, 0, stream>>>(W_in, W_mid, W_out, wt);

  // layer 0: t = S·x ; h = t @ W_in + b_in (stats[0] fused)
  agg_kernel<32><<<(NNODES * 32) / 256, 256, 0, stream>>>(xh, row_ofs, edges, dinv, (unsigned*)t);
  gemm_kernel<INDIM><<<gb, 256, 0, stream>>>((const unsigned short*)t, wt, b_in, h, stats);

  // layers 1..4
  for (int l = 1; l <= 4; l++) {
    bnapply_kernel<<<(NNODES * 16) / 256, 256, 0, stream>>>((const uint4*)h, stats + (size_t)(l - 1) * 256,
                                                            gamma + (size_t)(l - 1) * HID,
                                                            beta + (size_t)(l - 1) * HID, fh);
    agg_kernel<64><<<(NNODES * 64) / 256, 256, 0, stream>>>((const unsigned*)fh, row_ofs, edges, dinv, (unsigned*)t);
    const float* b = (l <= 3) ? (b_mid + (size_t)(l - 1) * HID) : b_out;
    const unsigned short* wl = wt + HID * 72 + (size_t)(l - 1) * HID * 136;
    gemm_kernel<HID><<<gb, 256, 0, stream>>>((const unsigned short*)t, wl, b, h, stats + (size_t)l * 256);
  }

  // final BN (no ReLU) on h4 -> d_out (fp32); fh region is dead by now.
  normout_kernel<<<(NNODES * 64) / 256, 256, 0, stream>>>((const unsigned*)h, stats + 4 * 256,
                                                          gamma + 4 * HID, beta + 4 * HID, (float2*)d_out);
}

// Round 7
// 692.381 us; speedup vs baseline: 1.0998x; 1.0998x over previous
//
#include <hip/hip_runtime.h>

#define NNODES 100000
#define NEDGES 1600000
#define HID    128
#define INDIM  64

typedef __attribute__((ext_vector_type(8))) short bf16x8;
typedef __attribute__((ext_vector_type(4))) float f32x4;
typedef __attribute__((ext_vector_type(2))) _Float16 half2_t;

__device__ __forceinline__ unsigned pack_bf16x2(float a, float b) {
  unsigned ua = __float_as_uint(a), ub = __float_as_uint(b);
  ua = (ua + 0x7fffu + ((ua >> 16) & 1u)) >> 16;
  ub = (ub + 0x7fffu + ((ub >> 16) & 1u)) >> 16;
  return ua | (ub << 16);
}
__device__ __forceinline__ unsigned short bf16r(float x) {
  unsigned u = __float_as_uint(x);
  u = (u + 0x7fffu + ((u >> 16) & 1u)) >> 16;
  return (unsigned short)u;
}
__device__ __forceinline__ float bf16lo(unsigned u) { return __uint_as_float(u << 16); }
__device__ __forceinline__ float bf16hi(unsigned u) { return __uint_as_float(u & 0xffff0000u); }
__device__ __forceinline__ unsigned f16x2(float a, float b) {
  half2_t h; h.x = (_Float16)a; h.y = (_Float16)b;
  return __builtin_bit_cast(unsigned, h);
}

// ============================ fused prep: xprep | wtprep | hist ============================
// Section A (blocks [0,XB)): x -> fp16.
// Section B ([XB,XB+WB)): W transpose -> bf16, layout [c][K]: [0,8192) layer0, then 4 x 16384.
// Section C (rest): u64 packed histogram (count [63:40], wdeg Q8.24 [39:0]); atomic return = rank.

#define XB ((NNODES * INDIM / 4) / 256)                 // 6250
#define WTOT (HID * INDIM + 4 * HID * HID)              // 73728
#define WB ((WTOT + 255) / 256)                         // 288
#define EB ((NEDGES + 255) / 256)                       // 6250

__global__ __launch_bounds__(256) void prep_kernel(const float* __restrict__ x, uint2* __restrict__ xh,
                                                   const float* __restrict__ W_in, const float* __restrict__ W_mid,
                                                   const float* __restrict__ W_out, unsigned short* __restrict__ wt,
                                                   const int* __restrict__ ei, const float* __restrict__ ew,
                                                   unsigned long long* __restrict__ packed,
                                                   unsigned* __restrict__ rank) {
  const int b = blockIdx.x;
  if (b < XB) {
    int i = b * 256 + threadIdx.x;
    float4 v = reinterpret_cast<const float4*>(x)[i];
    xh[i] = make_uint2(f16x2(v.x, v.y), f16x2(v.z, v.w));
  } else if (b < XB + WB) {
    int idx = (b - XB) * 256 + threadIdx.x;
    if (idx < WTOT) {
      float v;
      if (idx < HID * INDIM) {
        int c = idx / INDIM, k = idx % INDIM;
        v = W_in[(size_t)k * HID + c];
      } else {
        int r = idx - HID * INDIM;
        int l = r / (HID * HID), j = r % (HID * HID);
        int c = j / HID, k = j % HID;
        const float* W = (l < 3) ? (W_mid + (size_t)l * HID * HID) : W_out;
        v = W[(size_t)k * HID + c];
      }
      wt[idx] = bf16r(v);
    }
  } else {
    int e = (b - XB - WB) * 256 + threadIdx.x;
    if (e < NEDGES) {
      int d = ei[NEDGES + e];
      unsigned long long inc = (1ULL << 40) | (unsigned long long)(ew[e] * 16777216.0f + 0.5f);
      unsigned long long old = atomicAdd(&packed[d], inc);
      rank[e] = (unsigned)(old >> 40);
    }
  }
}

// ============================ scans (degcnt folded into scan1) ============================

__global__ __launch_bounds__(256) void scan1_kernel(const unsigned long long* __restrict__ packed,
                                                    unsigned* __restrict__ part, unsigned* __restrict__ bsums,
                                                    float* __restrict__ dinv) {
  __shared__ unsigned s[256];
  int i = blockIdx.x * 256 + threadIdx.x;
  unsigned v = 0u;
  if (i < NNODES) {
    unsigned long long r = packed[i];
    v = ((unsigned)(r >> 40) + 3u) & ~3u;                       // pad count to x4
    float wd = (float)(r & 0xFFFFFFFFFFULL) * (1.0f / 16777216.0f);
    dinv[i] = rsqrtf(wd + 1.0f);
  }
  s[threadIdx.x] = v;
  __syncthreads();
  for (int off = 1; off < 256; off <<= 1) {
    unsigned t = (threadIdx.x >= off) ? s[threadIdx.x - off] : 0u;
    __syncthreads();
    s[threadIdx.x] += t;
    __syncthreads();
  }
  if (i < NNODES) part[i] = s[threadIdx.x] - v;
  if (threadIdx.x == 255) bsums[blockIdx.x] = s[255];
}

__global__ void scan2_kernel(unsigned* __restrict__ bsums, unsigned* __restrict__ row_ofs, int nb) {
  __shared__ unsigned s[512];
  unsigned v = ((int)threadIdx.x < nb) ? bsums[threadIdx.x] : 0u;
  s[threadIdx.x] = v;
  __syncthreads();
  for (int off = 1; off < 512; off <<= 1) {
    unsigned t = (threadIdx.x >= off) ? s[threadIdx.x - off] : 0u;
    __syncthreads();
    s[threadIdx.x] += t;
    __syncthreads();
  }
  if ((int)threadIdx.x < nb) bsums[threadIdx.x] = s[threadIdx.x] - v;
  if (threadIdx.x == 511) row_ofs[NNODES] = s[511];
}

__global__ __launch_bounds__(256) void scan3_kernel(unsigned* __restrict__ row_ofs,
                                                    const unsigned* __restrict__ bsums) {
  int i = blockIdx.x * 256 + threadIdx.x;
  if (i < NNODES) row_ofs[i] += bsums[blockIdx.x];
}

// edges[pos] = {src, float_bits(norm)}; pos = padded row_ofs[d] + rank[e]; pad slots stay zeroed.
__global__ __launch_bounds__(256) void scatter_kernel(const int* __restrict__ ei, const float* __restrict__ ew,
                                                      const float* __restrict__ dinv,
                                                      const unsigned* __restrict__ rank,
                                                      const unsigned* __restrict__ row_ofs,
                                                      uint2* __restrict__ edges) {
  int e = blockIdx.x * 256 + threadIdx.x;
  if (e >= NEDGES) return;
  int s = ei[e];
  int d = ei[NEDGES + e];
  unsigned pos = row_ofs[d] + rank[e];
  uint2 rec;
  rec.x = (unsigned)s;
  rec.y = __float_as_uint(ew[e] * dinv[s] * dinv[d]);
  edges[pos] = rec;
}

// ============================ aggregation: t = S · fh (fp16 rows, fp32 accum) ============================
// LANES=64: one wave per node (scalar edge stream); LANES=32: two nodes per wave (layer 0).
// Edge lists padded to x4 with zero records; 8-wide main loop + 4-wide tail for deep MLP.

template <int LANES>
__global__ __launch_bounds__(256) void agg_kernel(const unsigned* __restrict__ hh,
                                                  const unsigned* __restrict__ row_ofs,
                                                  const uint2* __restrict__ edges,
                                                  const float* __restrict__ dinv,
                                                  unsigned* __restrict__ tb) {
  int gid = blockIdx.x * 256 + threadIdx.x;
  int node = gid / LANES;
  const int lane = gid % LANES;
  if (LANES == 64) node = __builtin_amdgcn_readfirstlane(node);
  const unsigned ro = row_ofs[node], re = row_ofs[node + 1];
  const float di = dinv[node];
  const float wself = di * di;
  half2_t sv = __builtin_bit_cast(half2_t, hh[(unsigned)node * LANES + lane]);
  float acc0 = (float)sv.x * wself;
  float acc1 = (float)sv.y * wself;
  unsigned e = ro;
  for (; e + 8 <= re; e += 8) {
    uint2 q0 = edges[e],     q1 = edges[e + 1], q2 = edges[e + 2], q3 = edges[e + 3];
    uint2 q4 = edges[e + 4], q5 = edges[e + 5], q6 = edges[e + 6], q7 = edges[e + 7];
    half2_t v0 = __builtin_bit_cast(half2_t, hh[q0.x * LANES + lane]);
    half2_t v1 = __builtin_bit_cast(half2_t, hh[q1.x * LANES + lane]);
    half2_t v2 = __builtin_bit_cast(half2_t, hh[q2.x * LANES + lane]);
    half2_t v3 = __builtin_bit_cast(half2_t, hh[q3.x * LANES + lane]);
    half2_t v4 = __builtin_bit_cast(half2_t, hh[q4.x * LANES + lane]);
    half2_t v5 = __builtin_bit_cast(half2_t, hh[q5.x * LANES + lane]);
    half2_t v6 = __builtin_bit_cast(half2_t, hh[q6.x * LANES + lane]);
    half2_t v7 = __builtin_bit_cast(half2_t, hh[q7.x * LANES + lane]);
    const float w0 = __uint_as_float(q0.y), w1 = __uint_as_float(q1.y);
    const float w2 = __uint_as_float(q2.y), w3 = __uint_as_float(q3.y);
    const float w4 = __uint_as_float(q4.y), w5 = __uint_as_float(q5.y);
    const float w6 = __uint_as_float(q6.y), w7 = __uint_as_float(q7.y);
    acc0 = fmaf((float)v0.x, w0, acc0); acc1 = fmaf((float)v0.y, w0, acc1);
    acc0 = fmaf((float)v1.x, w1, acc0); acc1 = fmaf((float)v1.y, w1, acc1);
    acc0 = fmaf((float)v2.x, w2, acc0); acc1 = fmaf((float)v2.y, w2, acc1);
    acc0 = fmaf((float)v3.x, w3, acc0); acc1 = fmaf((float)v3.y, w3, acc1);
    acc0 = fmaf((float)v4.x, w4, acc0); acc1 = fmaf((float)v4.y, w4, acc1);
    acc0 = fmaf((float)v5.x, w5, acc0); acc1 = fmaf((float)v5.y, w5, acc1);
    acc0 = fmaf((float)v6.x, w6, acc0); acc1 = fmaf((float)v6.y, w6, acc1);
    acc0 = fmaf((float)v7.x, w7, acc0); acc1 = fmaf((float)v7.y, w7, acc1);
  }
  if (e < re) {
    uint2 q0 = edges[e], q1 = edges[e + 1], q2 = edges[e + 2], q3 = edges[e + 3];
    half2_t v0 = __builtin_bit_cast(half2_t, hh[q0.x * LANES + lane]);
    half2_t v1 = __builtin_bit_cast(half2_t, hh[q1.x * LANES + lane]);
    half2_t v2 = __builtin_bit_cast(half2_t, hh[q2.x * LANES + lane]);
    half2_t v3 = __builtin_bit_cast(half2_t, hh[q3.x * LANES + lane]);
    const float w0 = __uint_as_float(q0.y), w1 = __uint_as_float(q1.y);
    const float w2 = __uint_as_float(q2.y), w3 = __uint_as_float(q3.y);
    acc0 = fmaf((float)v0.x, w0, acc0); acc1 = fmaf((float)v0.y, w0, acc1);
    acc0 = fmaf((float)v1.x, w1, acc0); acc1 = fmaf((float)v1.y, w1, acc1);
    acc0 = fmaf((float)v2.x, w2, acc0); acc1 = fmaf((float)v2.y, w2, acc1);
    acc0 = fmaf((float)v3.x, w3, acc0); acc1 = fmaf((float)v3.y, w3, acc1);
  }
  tb[(unsigned)node * LANES + lane] = pack_bf16x2(acc0, acc1);
}

// ============================ GEMM: W-stationary in VGPRs, persistent blocks ============================
// h = t @ W + b (bf16 out) + fused BN stats. Wt layout [c][K] (c = output col).
// Grid = 521 blocks x 3 panels of 64 rows. W frags loaded once into regs; only A goes through LDS.

#define GB 521   // ceil(1563/3)

template <int K>
__global__ __launch_bounds__(256) void gemm_kernel(const unsigned short* __restrict__ A,
                                                   const unsigned short* __restrict__ Wt,
                                                   const float* __restrict__ bias,
                                                   unsigned short* __restrict__ out,
                                                   float* __restrict__ stats) {
  constexpr int KP = K + 8;
  __shared__ __align__(16) unsigned short sA[64 * KP];
  __shared__ float sS[128], sQ[128];
  const int tid = threadIdx.x;
  if (tid < 128) { sS[tid] = 0.f; sQ[tid] = 0.f; }
  const int wid = tid >> 6;
  const int lane = tid & 63;
  const int wrow = wid * 16;
  const int fr = lane & 15;
  const int fk = (lane >> 4) * 8;

  // W fragments -> registers (L2-hot; amortized over 3 panels)
  bf16x8 wfrag[8][K / 32];
#pragma unroll
  for (int cf = 0; cf < 8; cf++)
#pragma unroll
    for (int ks = 0; ks < K / 32; ks++)
      wfrag[cf][ks] = *reinterpret_cast<const bf16x8*>(&Wt[(size_t)(cf * 16 + fr) * K + ks * 32 + fk]);
  float bv[8];
#pragma unroll
  for (int cf = 0; cf < 8; cf++) bv[cf] = bias[cf * 16 + fr];

  constexpr int CPR = K / 8;          // uint4 chunks per row
  const uint4* Ag = (const uint4*)A;
  const int orow = (lane >> 4) * 4;

  for (int pan = blockIdx.x; pan * 64 < NNODES; pan += GB) {
    const int row0 = pan * 64;
    __syncthreads();                  // sA safe to overwrite (also orders sS init on first pass)
#pragma unroll
    for (int i = tid; i < 64 * CPR; i += 256) {
      int row = i / CPR, ch = i % CPR;
      int grow = row0 + row;
      uint4 v = make_uint4(0u, 0u, 0u, 0u);
      if (grow < NNODES) v = Ag[(size_t)grow * CPR + ch];
      *reinterpret_cast<uint4*>(&sA[row * KP + ch * 8]) = v;
    }
    __syncthreads();

    f32x4 acc[8];
#pragma unroll
    for (int cf = 0; cf < 8; cf++) acc[cf] = (f32x4){0.f, 0.f, 0.f, 0.f};
    bf16x8 afrag[K / 32];
#pragma unroll
    for (int ks = 0; ks < K / 32; ks++)
      afrag[ks] = *reinterpret_cast<const bf16x8*>(&sA[(wrow + fr) * KP + ks * 32 + fk]);
#pragma unroll
    for (int cf = 0; cf < 8; cf++)
#pragma unroll
      for (int ks = 0; ks < K / 32; ks++)
        acc[cf] = __builtin_amdgcn_mfma_f32_16x16x32_bf16(afrag[ks], wfrag[cf][ks], acc[cf], 0, 0, 0);

#pragma unroll
    for (int cf = 0; cf < 8; cf++) {
      const int col = cf * 16 + fr;
      float s = 0.f, q = 0.f;
#pragma unroll
      for (int j = 0; j < 4; j++) {
        int grow = row0 + wrow + orow + j;
        float val = 0.f;
        if (grow < NNODES) {
          unsigned short o = bf16r(acc[cf][j] + bv[cf]);
          out[(size_t)grow * HID + col] = o;
          val = __uint_as_float((unsigned)o << 16);
        }
        s += val; q += val * val;
      }
      s += __shfl_xor(s, 16); s += __shfl_xor(s, 32);
      q += __shfl_xor(q, 16); q += __shfl_xor(q, 32);
      if (lane < 16) { atomicAdd(&sS[col], s); atomicAdd(&sQ[col], q); }
    }
  }
  __syncthreads();
  if (tid < 128) {
    atomicAdd(&stats[tid],       sS[tid]);
    atomicAdd(&stats[128 + tid], sQ[tid]);
  }
}

// ============================ BN apply (inline finalize): fh = relu(bn(h)) fp16 ============================

__global__ __launch_bounds__(256) void bnapply_kernel(const uint4* __restrict__ hb,
                                                      const float* __restrict__ stats,
                                                      const float* __restrict__ gamma,
                                                      const float* __restrict__ beta,
                                                      uint4* __restrict__ fh) {
  __shared__ float sc[128], sh[128];
  if (threadIdx.x < 128) {
    int c = threadIdx.x;
    float mu  = stats[c] * (1.0f / NNODES);
    float var = fmaf(-mu, mu, stats[128 + c] * (1.0f / NNODES));
    float scale = gamma[c] * rsqrtf(var + 1e-5f);
    sc[c] = scale;
    sh[c] = fmaf(-mu, scale, beta[c]);
  }
  __syncthreads();
  int i = blockIdx.x * 256 + threadIdx.x;   // grid exact: N*16/256
  uint4 v = hb[i];
  int cb = (i & 15) * 8;
  float r0 = fmaxf(fmaf(bf16lo(v.x), sc[cb + 0], sh[cb + 0]), 0.f);
  float r1 = fmaxf(fmaf(bf16hi(v.x), sc[cb + 1], sh[cb + 1]), 0.f);
  float r2 = fmaxf(fmaf(bf16lo(v.y), sc[cb + 2], sh[cb + 2]), 0.f);
  float r3 = fmaxf(fmaf(bf16hi(v.y), sc[cb + 3], sh[cb + 3]), 0.f);
  float r4 = fmaxf(fmaf(bf16lo(v.z), sc[cb + 4], sh[cb + 4]), 0.f);
  float r5 = fmaxf(fmaf(bf16hi(v.z), sc[cb + 5], sh[cb + 5]), 0.f);
  float r6 = fmaxf(fmaf(bf16lo(v.w), sc[cb + 6], sh[cb + 6]), 0.f);
  float r7 = fmaxf(fmaf(bf16hi(v.w), sc[cb + 7], sh[cb + 7]), 0.f);
  fh[i] = make_uint4(f16x2(r0, r1), f16x2(r2, r3), f16x2(r4, r5), f16x2(r6, r7));
}

// ============================ final BN (no ReLU) -> fp32 out ============================

__global__ __launch_bounds__(256) void normout_kernel(const unsigned* __restrict__ hb,
                                                      const float* __restrict__ stats,
                                                      const float* __restrict__ gamma,
                                                      const float* __restrict__ beta,
                                                      float2* __restrict__ out) {
  __shared__ float sc[128], sh[128];
  if (threadIdx.x < 128) {
    int c = threadIdx.x;
    float mu  = stats[c] * (1.0f / NNODES);
    float var = fmaf(-mu, mu, stats[128 + c] * (1.0f / NNODES));
    float scale = gamma[c] * rsqrtf(var + 1e-5f);
    sc[c] = scale;
    sh[c] = fmaf(-mu, scale, beta[c]);
  }
  __syncthreads();
  int i = blockIdx.x * 256 + threadIdx.x;   // grid exact: N*64/256
  unsigned u = hb[i];
  int c = (i & 63) * 2;
  out[i] = make_float2(fmaf(bf16lo(u), sc[c],     sh[c]),
                       fmaf(bf16hi(u), sc[c + 1], sh[c + 1]));
}

// ============================ launch ============================

extern "C" void kernel_launch(void* const* d_in, const int* in_sizes, int n_in,
                              void* d_out, int out_size, void* d_ws, size_t ws_size,
                              hipStream_t stream) {
  const float* x     = (const float*)d_in[0];
  const int*   ei    = (const int*)d_in[1];
  const float* ew    = (const float*)d_in[2];
  const float* W_in  = (const float*)d_in[3];
  const float* b_in  = (const float*)d_in[4];
  const float* W_mid = (const float*)d_in[5];
  const float* b_mid = (const float*)d_in[6];
  const float* W_out = (const float*)d_in[7];
  const float* b_out = (const float*)d_in[8];
  const float* gamma = (const float*)d_in[9];
  const float* beta  = (const float*)d_in[10];

  char* p = (char*)d_ws;
  auto alloc = [&](size_t bytes) -> char* {
    char* r = p;
    p += (bytes + 255) & ~(size_t)255;
    return r;
  };
  const size_t EPAD = (size_t)NEDGES + 3 * (size_t)NNODES + 8;
  unsigned long long* packed = (unsigned long long*)alloc((size_t)NNODES * 8);
  float*    stats   = (float*)alloc(5 * 256 * 4);
  uint2*    edges   = (uint2*)alloc(EPAD * 8);
  size_t zbytes = (size_t)(p - (char*)d_ws);          // packed + stats + edges zeroed
  float*    dinv    = (float*)alloc((size_t)NNODES * 4);
  unsigned* row_ofs = (unsigned*)alloc((size_t)(NNODES + 1) * 4);
  unsigned* bsums   = (unsigned*)alloc(512 * 4);
  unsigned* rank    = (unsigned*)alloc((size_t)NEDGES * 4);
  unsigned* xh      = (unsigned*)alloc((size_t)NNODES * INDIM * 2);
  unsigned short* h = (unsigned short*)alloc((size_t)NNODES * HID * 2);
  unsigned short* t = (unsigned short*)alloc((size_t)NNODES * HID * 2);
  unsigned short* wt = (unsigned short*)alloc((size_t)WTOT * 2);
  uint4*    fh      = (uint4*)d_out;                  // fp16 f(h) scratch in d_out (25.6 of 51.2 MB)

  hipMemsetAsync(d_ws, 0, zbytes, stream);

  const int nb = (NNODES + 255) / 256;

  prep_kernel<<<XB + WB + EB, 256, 0, stream>>>(x, (uint2*)xh, W_in, W_mid, W_out, wt, ei, ew, packed, rank);
  scan1_kernel<<<nb, 256, 0, stream>>>(packed, row_ofs, bsums, dinv);
  scan2_kernel<<<1, 512, 0, stream>>>(bsums, row_ofs, nb);
  scan3_kernel<<<nb, 256, 0, stream>>>(row_ofs, bsums);
  scatter_kernel<<<EB, 256, 0, stream>>>(ei, ew, dinv, rank, row_ofs, edges);

  // layer 0: t = S·x ; h = t @ W_in + b_in (stats[0] fused)
  agg_kernel<32><<<(NNODES * 32) / 256, 256, 0, stream>>>(xh, row_ofs, edges, dinv, (unsigned*)t);
  gemm_kernel<INDIM><<<GB, 256, 0, stream>>>((const unsigned short*)t, wt, b_in, h, stats);

  // layers 1..4
  for (int l = 1; l <= 4; l++) {
    bnapply_kernel<<<(NNODES * 16) / 256, 256, 0, stream>>>((const uint4*)h, stats + (size_t)(l - 1) * 256,
                                                            gamma + (size_t)(l - 1) * HID,
                                                            beta + (size_t)(l - 1) * HID, fh);
    agg_kernel<64><<<(NNODES * 64) / 256, 256, 0, stream>>>((const unsigned*)fh, row_ofs, edges, dinv, (unsigned*)t);
    const float* b = (l <= 3) ? (b_mid + (size_t)(l - 1) * HID) : b_out;
    const unsigned short* wl = wt + HID * INDIM + (size_t)(l - 1) * HID * HID;
    gemm_kernel<HID><<<GB, 256, 0, stream>>>((const unsigned short*)t, wl, b, h, stats + (size_t)l * 256);
  }

  // final BN (no ReLU) on h4 -> d_out (fp32); fh region dead by now.
  normout_kernel<<<(NNODES * 64) / 256, 256, 0, stream>>>((const unsigned*)h, stats + 4 * 256,
                                                          gamma + 4 * HID, beta + 4 * HID, (float2*)d_out);
}